// Round 12
// baseline (21655.078 us; speedup 1.0000x reference)
//
#include <hip/hip_runtime.h>
#include <stdint.h>

// PointerNet fused forward. B=512, S=50, E=H=128.
// 512 blocks x 512 threads (8 waves), ONE batch element per block (GPB=1).
// Rationale (R12): be-amortized structures need ~100 VGPR; 1024-thread
// blocks cap at 64 VGPR on this toolchain (R8/R9/R11 all spilled). Instead:
// 512-thread blocks with LDS <= ~55 KB -> 2 blocks/CU -> 16 waves/CU =
// 4 waves/SIMD at VGPR<=128, with INDEPENDENT barriers per block (better
// overlap than intra-block waves). Trade: weight L2 traffic doubles
// (16.5 -> 33 GB) -- acceptable, R7 ran at 36% of the L2 ceiling.
// Lane role: u = w*16 + (l&15) (unit), q = l>>4 (k-quarter, 8 k4 each).
// Quarter-split f64 dots, butterfly shfl_xor(16)+shfl_xor(32) (all lanes get
// the full sum -> c replicated x4, deterministic). Writers q==0.
// Numerics identical to passing rounds 5-11: full-f64 dots, gate sum
// f_add(f_add(f_add((float)di,bih),(float)ei),bhh), XLA tanh poly,
// logistic-as-tanh, sequential softmax sum, f64 attention dots (R8's
// verified 8-lane/row logits code).
// Sampling: jax.random.categorical, THREEFRY PARTITIONABLE mode:
//   fold_in: key' = tf2x32(key, (0, t))
//   split (foldlike): k1 = tf2x32(key', (0, 0))   [both output words]
//   random_bits(32): bits[j] = o0 ^ o1 of tf2x32(k1, (0, j))
// gumbel exactly as jax._src.random; argmax with first-index ties.
// All cross-lane communication: LDS write -> __syncthreads -> read, or
// register shuffles (round-5 hardening).

#define OFF_PIH_E 0
#define OFF_PHH_E 65536
#define OFF_PIH_D 131072
#define OFF_PHH_D 196608
#define OFF_PQG   262144
#define OFF_PRG   278528
#define OFF_PQP   294912
#define OFF_PRP   311296
// ws total: 327680 floats = 1.31 MB

#define RSTR 132   // LDS row stride for RG/RP (16B-aligned)

#define TINYF 1.1754943508222875e-38f

static __device__ __forceinline__ float f_add(float a, float b){ return __fadd_rn(a,b); }
static __device__ __forceinline__ float f_mul(float a, float b){ return __fmul_rn(a,b); }
static __device__ __forceinline__ float f_sub(float a, float b){ return __fsub_rn(a,b); }

static __device__ __forceinline__ double shfl_xor_d(double v, int mask) {
  long long x = __double_as_longlong(v);
  int lo = (int)(x & 0xffffffffll);
  int hi = (int)(x >> 32);
  lo = __shfl_xor(lo, mask);
  hi = __shfl_xor(hi, mask);
  return __longlong_as_double(((long long)hi << 32) | (unsigned long long)(unsigned int)lo);
}
#define RED2(x) { x += shfl_xor_d(x, 16); x += shfl_xor_d(x, 32); }

// XLA CPU tanh: elemental_ir_emitter rational approximation, unfused mul/add.
static __device__ __forceinline__ float tanh_xla(float x) {
  float xc = fminf(fmaxf(x, -7.90531110763549805f), 7.90531110763549805f);
  float x2 = f_mul(xc, xc);
  float p;
  p = -2.76076847742355e-16f;
  p = f_add(f_mul(p, x2),  2.00018790482477e-13f);
  p = f_add(f_mul(p, x2), -8.60467152213735e-11f);
  p = f_add(f_mul(p, x2),  5.12229709037114e-08f);
  p = f_add(f_mul(p, x2),  1.48572235717979e-05f);
  p = f_add(f_mul(p, x2),  6.37261928875436e-04f);
  p = f_add(f_mul(p, x2),  4.89352455891786e-03f);
  p = f_mul(xc, p);
  float q;
  q = 1.19825839466702e-06f;
  q = f_add(f_mul(q, x2), 1.18534705686654e-04f);
  q = f_add(f_mul(q, x2), 2.26843463243900e-03f);
  q = f_add(f_mul(q, x2), 4.89352518554385e-03f);
  float r = __fdiv_rn(p, q);
  return (fabsf(x) < 0.0004f) ? x : r;
}

// XLA logistic expansion: 0.5 + 0.5*tanh(0.5*x)
static __device__ __forceinline__ float sigmoid_xla(float x) {
  return f_add(0.5f, f_mul(0.5f, tanh_xla(f_mul(0.5f, x))));
}

// Threefry-2x32, 20 rounds (JAX key schedule)
static __device__ __forceinline__ void tf2x32(uint32_t k0, uint32_t k1,
                                              uint32_t x0, uint32_t x1,
                                              uint32_t &o0, uint32_t &o1) {
  uint32_t ks2 = k0 ^ k1 ^ 0x1BD11BDAu;
  x0 += k0; x1 += k1;
#define TFR(r) { x0 += x1; x1 = (x1 << (r)) | (x1 >> (32 - (r))); x1 ^= x0; }
  TFR(13) TFR(15) TFR(26) TFR(6)
  x0 += k1;  x1 += ks2 + 1u;
  TFR(17) TFR(29) TFR(16) TFR(24)
  x0 += ks2; x1 += k0 + 2u;
  TFR(13) TFR(15) TFR(26) TFR(6)
  x0 += k0;  x1 += k1 + 3u;
  TFR(17) TFR(29) TFR(16) TFR(24)
  x0 += k1;  x1 += ks2 + 4u;
  TFR(13) TFR(15) TFR(26) TFR(6)
  x0 += ks2; x1 += k0 + 5u;
#undef TFR
  o0 = x0; o1 = x1;
}

// NOTE: parameter names must not collide with float4 member names (.x/.y/.z/.w)
#define ACC4(acc, Wv, Vv) \
  acc = fma((double)(Wv).x, (double)(Vv).x, acc); \
  acc = fma((double)(Wv).y, (double)(Vv).y, acc); \
  acc = fma((double)(Wv).z, (double)(Vv).z, acc); \
  acc = fma((double)(Wv).w, (double)(Vv).w, acc);

// Pack weights: LSTM [512,128] -> P[(k>>2)*2048 + r*4 + (k&3)]
//               attn [128,128] -> P[(k>>2)*512  + o*4 + (k&3)]
__global__ void prep_kernel(const float* __restrict__ eWih, const float* __restrict__ eWhh,
                            const float* __restrict__ dWih, const float* __restrict__ dWhh,
                            const float* __restrict__ gWq,  const float* __restrict__ gWref,
                            const float* __restrict__ pWq,  const float* __restrict__ pWref,
                            float* __restrict__ ws) {
  int id = blockIdx.x * blockDim.x + threadIdx.x;
  if (id < 262144) {
    int m = id >> 16, e = id & 65535;
    const float* src = (m == 0) ? eWih : (m == 1) ? eWhh : (m == 2) ? dWih : dWhh;
    int r = e >> 7, k = e & 127;
    ws[m * 65536 + (k >> 2) * 2048 + r * 4 + (k & 3)] = src[e];
  } else if (id < 327680) {
    int a = id - 262144;
    int m = a >> 14, e = a & 16383;
    const float* src = (m == 0) ? gWq : (m == 1) ? gWref : (m == 2) ? pWq : pWref;
    int o = e >> 7, k = e & 127;
    ws[262144 + m * 16384 + (k >> 2) * 512 + o * 4 + (k & 3)] = src[e];
  }
}

// Quarter-k LSTM step, single batch element. All lanes end with full sums
// (butterfly) -> gate math replicated x4 (deterministic); returns h_new.
static __device__ __forceinline__ float lstm_q(
    int u, int q,
    const float4* __restrict__ PIH, const float4* __restrict__ PHH,
    const float* __restrict__ bih, const float* __restrict__ bhh,
    const float4* __restrict__ xr, const float4* __restrict__ hr,
    float &c)
{
  double di = 0, df = 0, dg = 0, dd = 0;
  double ei = 0, ef = 0, eg = 0, eo = 0;
  const int kb = q * 8;
#pragma unroll
  for (int kk = 0; kk < 8; kk++) {
    int k4 = kb + ((kk + 2 * q) & 7);     // per-quarter rotation: bank-spread
    float4 w0 = PIH[k4 * 512 + u];
    float4 w1 = PIH[k4 * 512 + u + 128];
    float4 w2 = PIH[k4 * 512 + u + 256];
    float4 w3 = PIH[k4 * 512 + u + 384];
    float4 xv = xr[k4];
    ACC4(di, w0, xv) ACC4(df, w1, xv) ACC4(dg, w2, xv) ACC4(dd, w3, xv)
    float4 v0 = PHH[k4 * 512 + u];
    float4 v1 = PHH[k4 * 512 + u + 128];
    float4 v2 = PHH[k4 * 512 + u + 256];
    float4 v3 = PHH[k4 * 512 + u + 384];
    float4 hv = hr[k4];
    ACC4(ei, v0, hv) ACC4(ef, v1, hv) ACC4(eg, v2, hv) ACC4(eo, v3, hv)
  }
  RED2(di) RED2(df) RED2(dg) RED2(dd)
  RED2(ei) RED2(ef) RED2(eg) RED2(eo)
  // ((x@Wih^T + bih) + h@Whh^T) + bhh  -- XLA add tree order
  float gi = f_add(f_add(f_add((float)di, bih[u      ]), (float)ei), bhh[u      ]);
  float gf = f_add(f_add(f_add((float)df, bih[u + 128]), (float)ef), bhh[u + 128]);
  float gg = f_add(f_add(f_add((float)dg, bih[u + 256]), (float)eg), bhh[u + 256]);
  float go = f_add(f_add(f_add((float)dd, bih[u + 384]), (float)eo), bhh[u + 384]);
  float I = sigmoid_xla(gi);
  float F = sigmoid_xla(gf);
  float G = tanh_xla(gg);
  float O = sigmoid_xla(go);
  c = f_add(f_mul(F, c), f_mul(I, G));
  return f_mul(O, tanh_xla(c));
}

__global__ void __launch_bounds__(512)
pnet_kernel(const float* __restrict__ bi, const float* __restrict__ emb,
            const float* __restrict__ ebih, const float* __restrict__ ebhh,
            const float* __restrict__ dbih, const float* __restrict__ dbhh,
            const float* __restrict__ gbq, const float* __restrict__ gbref, const float* __restrict__ gV,
            const float* __restrict__ pbq, const float* __restrict__ pbref, const float* __restrict__ pV,
            const float* __restrict__ dstart,
            float* __restrict__ ws, float* __restrict__ out)
{
  __shared__ __align__(16) float sRG[50 * RSTR];   // 26.4 KB
  __shared__ __align__(16) float sRP[50 * RSTR];   // 26.4 KB
  __shared__ __align__(16) float sh_x[128];
  __shared__ __align__(16) float sh_h[128];
  __shared__ __align__(16) float sh_q[128];
  __shared__ __align__(16) float sh_q2[128];
  __shared__ float sh_att[64];
  __shared__ float sh_w[64];
  __shared__ unsigned long long sh_msk;
  __shared__ int sh_idx;

  const int tid = threadIdx.x;              // 0..511
  const int l   = tid & 63;                 // lane
  const int w   = tid >> 6;                 // wave 0..7
  const int u   = w * 16 + (l & 15);        // unit 0..127
  const int q   = l >> 4;                   // k-quarter 0..3
  const bool wr = (q == 0);                 // writer lanes
  const int gb  = blockIdx.x;               // batch element

  const float4* PIH_E = (const float4*)(ws + OFF_PIH_E);
  const float4* PHH_E = (const float4*)(ws + OFF_PHH_E);
  const float4* PIH_D = (const float4*)(ws + OFF_PIH_D);
  const float4* PHH_D = (const float4*)(ws + OFF_PHH_D);
  const float4* PQG = (const float4*)(ws + OFF_PQG);
  const float4* PRG = (const float4*)(ws + OFF_PRG);
  const float4* PQP = (const float4*)(ws + OFF_PQP);
  const float4* PRP = (const float4*)(ws + OFF_PRP);

  const float NEG_INF = -__builtin_inff();

  if (tid < 128) sh_h[tid] = 0.0f;
  if (tid == 0) sh_msk = 0ull;
  float c_st = 0.0f;                        // cell state (replicated x4 lanes)
  __syncthreads();

  // ---------------- encoder + fused ref projections ----------------
  for (int t = 0; t < 50; t++) {
    if (tid < 128) {
      float x0 = bi[gb * 100 + t];
      float x1 = bi[gb * 100 + 50 + t];
      sh_x[tid] = __fmaf_rn(x1, emb[128 + tid], f_mul(x0, emb[tid]));
    }
    __syncthreads();                               // E1: x ready
    float hn = lstm_q(u, q, PIH_E, PHH_E, ebih, ebhh,
                      (const float4*)sh_x, (const float4*)sh_h, c_st);
    __syncthreads();                               // E2: dots done, h free
    if (wr) sh_h[u] = hn;
    __syncthreads();                               // E3: h ready
    // rg/rp[t][u] (Conv1d k=1 fused)
    {
      double ag = 0, ap = 0;
      const float4* hr = (const float4*)sh_h;
      const int kb = q * 8;
#pragma unroll
      for (int kk = 0; kk < 8; kk++) {
        int k4 = kb + ((kk + 2 * q) & 7);
        float4 wg = PRG[k4 * 128 + u];
        float4 wp = PRP[k4 * 128 + u];
        float4 hv = hr[k4];
        ACC4(ag, wg, hv) ACC4(ap, wp, hv)
      }
      RED2(ag) RED2(ap)
      if (wr) {
        sRG[t * RSTR + u] = f_add((float)ag, gbref[u]);
        sRP[t * RSTR + u] = f_add((float)ap, pbref[u]);
      }
    }
    // loop-top sh_x write guarded by E1; refproj ignores sh_x.
  }
  if (tid < 128) sh_x[tid] = dstart[tid];   // decoder initial input
  __syncthreads();

  // ---------------- decoder ----------------
  for (int t = 0; t < 50; t++) {
    // partitionable threefry:
    //   fk = fold_in(key(42), t) = tf((0,42), (0,t))
    //   k1 = split(fk, 2)[0]     = tf(fk, (0,0))   [foldlike: both words]
    uint32_t f0, f1, k1a, k1b;
    tf2x32(0u, 42u, 0u, (uint32_t)t, f0, f1);
    tf2x32(f0, f1, 0u, 0u, k1a, k1b);

    float hn = lstm_q(u, q, PIH_D, PHH_D, dbih, dbhh,
                      (const float4*)sh_x, (const float4*)sh_h, c_st);
    __syncthreads();                               // B1: dots done
    if (wr) sh_h[u] = hn;
    __syncthreads();                               // B2: h ready

    // glimpse query: qg = Wq_g @ h + bq_g
    {
      double a = 0;
      const float4* hr = (const float4*)sh_h;
      const int kb = q * 8;
#pragma unroll
      for (int kk = 0; kk < 8; kk++) {
        int k4 = kb + ((kk + 2 * q) & 7);
        float4 wv = PQG[k4 * 128 + u];
        float4 xv = hr[k4];
        ACC4(a, wv, xv)
      }
      RED2(a)
      if (wr) sh_q[u] = f_add((float)a, gbq[u]);
    }
    __syncthreads();                               // B3

    // glimpse logits: lg[s] = sum_h V[h]*tanh(qg[h]+ref_g[s][h]); 8 lanes/row
    {
      double acc = 0.0;
      const int s = tid >> 3;
      const int f4o = (tid & 7) * 4;
      if (tid < 400) {
        const float4* rr = (const float4*)(&sRG[s * RSTR]) + f4o;
        const float4* qq = (const float4*)sh_q + f4o;
        const float4* vvp = (const float4*)gV + f4o;
#pragma unroll
        for (int k4 = 0; k4 < 4; k4++) {
          float4 rv = rr[k4];
          float4 qv = qq[k4];
          float4 gvv = vvp[k4];
          acc = fma((double)gvv.x, (double)tanh_xla(f_add(qv.x, rv.x)), acc);
          acc = fma((double)gvv.y, (double)tanh_xla(f_add(qv.y, rv.y)), acc);
          acc = fma((double)gvv.z, (double)tanh_xla(f_add(qv.z, rv.z)), acc);
          acc = fma((double)gvv.w, (double)tanh_xla(f_add(qv.w, rv.w)), acc);
        }
      }
      double tot = acc + shfl_xor_d(acc, 1);
      tot = tot + shfl_xor_d(tot, 2);
      tot = tot + shfl_xor_d(tot, 4);
      if (tid < 400 && (tid & 7) == 0) {
        float lg = (float)tot;
        sh_att[s] = ((sh_msk >> s) & 1ull) ? NEG_INF : lg;
      }
      if (tid >= 400 && tid < 414) sh_att[tid - 350] = NEG_INF;  // pad 50..63
    }
    __syncthreads();                               // B4

    // glimpse softmax: wave 0
    if (w == 0) {
      float v = sh_att[l];
      float m = v;
      for (int off = 32; off > 0; off >>= 1) m = fmaxf(m, __shfl_xor(m, off));
      float ex = (l < 50) ? expf(f_sub(v, m)) : 0.0f;
      float ss = 0.0f;
      for (int s2 = 0; s2 < 50; s2++) ss = f_add(ss, __shfl(ex, s2));
      float wv = __fdiv_rn(ex, ss);
      sh_w[l] = (l < 50) ? wv : 0.0f;
    }
    __syncthreads();                               // B5

    // q2 = sum_s w[s]*ref_g[s][:]; s-halves by (q&1), combine xor16
    {
      double a = 0;
      const int s0 = (q & 1) * 25;
      for (int s2 = s0; s2 < s0 + 25; s2++) {
        a = fma((double)sRG[s2 * RSTR + u], (double)sh_w[s2], a);
      }
      a += shfl_xor_d(a, 16);
      if (wr) sh_q2[u] = (float)a;
    }
    __syncthreads();                               // B6

    // pointer query: qp = Wq_p @ q2 + bq_p
    {
      double a = 0;
      const float4* qr = (const float4*)sh_q2;
      const int kb = q * 8;
#pragma unroll
      for (int kk = 0; kk < 8; kk++) {
        int k4 = kb + ((kk + 2 * q) & 7);
        float4 wv = PQP[k4 * 128 + u];
        float4 xv = qr[k4];
        ACC4(a, wv, xv)
      }
      RED2(a)
      if (wr) sh_q[u] = f_add((float)a, pbq[u]);
    }
    __syncthreads();                               // B7

    // pointer logits + 10*tanh + mask; 8 lanes/row
    {
      double acc = 0.0;
      const int s = tid >> 3;
      const int f4o = (tid & 7) * 4;
      if (tid < 400) {
        const float4* rr = (const float4*)(&sRP[s * RSTR]) + f4o;
        const float4* qq = (const float4*)sh_q + f4o;
        const float4* vvp = (const float4*)pV + f4o;
#pragma unroll
        for (int k4 = 0; k4 < 4; k4++) {
          float4 rv = rr[k4];
          float4 qv = qq[k4];
          float4 pvv = vvp[k4];
          acc = fma((double)pvv.x, (double)tanh_xla(f_add(qv.x, rv.x)), acc);
          acc = fma((double)pvv.y, (double)tanh_xla(f_add(qv.y, rv.y)), acc);
          acc = fma((double)pvv.z, (double)tanh_xla(f_add(qv.z, rv.z)), acc);
          acc = fma((double)pvv.w, (double)tanh_xla(f_add(qv.w, rv.w)), acc);
        }
      }
      double tot = acc + shfl_xor_d(acc, 1);
      tot = tot + shfl_xor_d(tot, 2);
      tot = tot + shfl_xor_d(tot, 4);
      if (tid < 400 && (tid & 7) == 0) {
        float lp = (float)tot;
        lp = f_mul(10.0f, tanh_xla(lp));
        sh_att[s] = ((sh_msk >> s) & 1ull) ? NEG_INF : lp;
      }
      if (tid >= 400 && tid < 414) sh_att[tid - 350] = NEG_INF;
    }
    __syncthreads();                               // B8

    // probs output + gumbel sampling: wave 0
    if (w == 0) {
      float v = sh_att[l];
      float m = v;
      for (int off = 32; off > 0; off >>= 1) m = fmaxf(m, __shfl_xor(m, off));
      float ex = (l < 50) ? expf(f_sub(v, m)) : 0.0f;
      float ss = 0.0f;
      for (int s2 = 0; s2 < 50; s2++) ss = f_add(ss, __shfl(ex, s2));
      if (l < 50) out[t * 25600 + gb * 50 + l] = __fdiv_rn(ex, ss);

      float val = NEG_INF;
      int ii = l;
      if (l < 50) {
        int j = gb * 50 + l;               // flat index into (B,S) gumbel draw
        uint32_t b0, b1;
        tf2x32(k1a, k1b, 0u, (uint32_t)j, b0, b1);
        uint32_t bits = b0 ^ b1;
        float fl = __uint_as_float((bits >> 9) | 0x3f800000u) - 1.0f;  // [0,1)
        float uu = f_add(fl, TINYF);
        uu = fmaxf(TINYF, uu);
        float gum = -logf(-logf(uu));
        val = f_add(v, gum);               // -inf stays -inf for masked
      }
      // argmax, first-index tiebreak (jnp.argmax semantics)
      for (int off = 32; off > 0; off >>= 1) {
        float ov = __shfl_down(val, off);
        int   oi = __shfl_down(ii, off);
        if (ov > val || (ov == val && oi < ii)) { val = ov; ii = oi; }
      }
      if (l == 0) {
        sh_idx = ii;
        sh_msk |= (1ull << ii);            // masks step t+1 onward
        out[1280000 + t * 512 + gb] = (float)ii;
      }
    }
    __syncthreads();                               // B9

    // next decoder input: embedded[b, idx]
    if (tid < 128) {
      int idx = sh_idx;
      float x0 = bi[gb * 100 + idx];
      float x1 = bi[gb * 100 + 50 + idx];
      sh_x[tid] = __fmaf_rn(x1, emb[128 + tid], f_mul(x0, emb[tid]));
    }
    __syncthreads();                               // B10
  }
}

extern "C" void kernel_launch(void* const* d_in, const int* in_sizes, int n_in,
                              void* d_out, int out_size, void* d_ws, size_t ws_size,
                              hipStream_t stream) {
  const float* bi     = (const float*)d_in[0];
  const float* emb    = (const float*)d_in[1];
  const float* eWih   = (const float*)d_in[2];
  const float* eWhh   = (const float*)d_in[3];
  const float* ebih   = (const float*)d_in[4];
  const float* ebhh   = (const float*)d_in[5];
  const float* dWih   = (const float*)d_in[6];
  const float* dWhh   = (const float*)d_in[7];
  const float* dbih   = (const float*)d_in[8];
  const float* dbhh   = (const float*)d_in[9];
  const float* gWq    = (const float*)d_in[10];
  const float* gbq    = (const float*)d_in[11];
  const float* gWref  = (const float*)d_in[12];
  const float* gbref  = (const float*)d_in[13];
  const float* gV     = (const float*)d_in[14];
  const float* pWq    = (const float*)d_in[15];
  const float* pbq    = (const float*)d_in[16];
  const float* pWref  = (const float*)d_in[17];
  const float* pbref  = (const float*)d_in[18];
  const float* pV     = (const float*)d_in[19];
  const float* dstart = (const float*)d_in[20];
  float* ws  = (float*)d_ws;
  float* out = (float*)d_out;

  hipLaunchKernelGGL(prep_kernel, dim3(1280), dim3(256), 0, stream,
                     eWih, eWhh, dWih, dWhh, gWq, gWref, pWq, pWref, ws);
  hipLaunchKernelGGL(pnet_kernel, dim3(512), dim3(512), 0, stream,
                     bi, emb, ebih, ebhh, dbih, dbhh,
                     gbq, gbref, gV, pbq, pbref, pV, dstart, ws, out);
}

// Round 13
// 1963.155 us; speedup vs baseline: 11.0308x; 11.0308x over previous
//
#include <hip/hip_runtime.h>
#include <stdint.h>

// PointerNet fused forward. B=512, S=50, E=H=128.
// 512 blocks x 512 threads (8 waves), ONE batch element per block (GPB=1).
// R13: R12's occupancy plan (2 blocks/CU x 8 waves = 16 waves/CU = 4/SIMD)
// with SPILL-PROOF ADDRESSING. R12 spilled (WRITE 1.3 GB scratch, FETCH 25 GB)
// because the rotated quarter indexing ((kk+2q)&7, full unroll) defeated
// strength reduction. Fix: stride-4 interleaved k-split -- quarter q owns
// k4 = 4*kk+q, so weight offsets advance by one induction variable
// (2048 float4/iter) and the 4 quarters' concurrent LDS x/h reads hit
// distinct bank groups (no rotation needed). #pragma unroll 2 caps
// transient register pressure.
// Lane role: u = w*16 + (l&15) (unit), q = l>>4 (k-quarter, stride-4).
// f64 dots + butterfly shfl_xor(16)+shfl_xor(32) (all lanes full sum ->
// c replicated x4, deterministic). Writers q==0.
// Numerics identical to passing rounds: full-f64 dots, gate sum
// f_add(f_add(f_add((float)di,bih),(float)ei),bhh), XLA tanh poly,
// logistic-as-tanh, sequential softmax sum, f64 attention dots.
// Sampling: jax.random.categorical, THREEFRY PARTITIONABLE mode:
//   fold_in: key' = tf2x32(key, (0, t))
//   split (foldlike): k1 = tf2x32(key', (0, 0))   [both output words]
//   random_bits(32): bits[j] = o0 ^ o1 of tf2x32(k1, (0, j))
// gumbel exactly as jax._src.random; argmax with first-index ties.
// All cross-lane communication: LDS write -> __syncthreads -> read, or
// register shuffles (round-5 hardening).

#define OFF_PIH_E 0
#define OFF_PHH_E 65536
#define OFF_PIH_D 131072
#define OFF_PHH_D 196608
#define OFF_PQG   262144
#define OFF_PRG   278528
#define OFF_PQP   294912
#define OFF_PRP   311296
// ws total: 327680 floats = 1.31 MB

#define RSTR 132   // LDS row stride for RG/RP (16B-aligned)

#define TINYF 1.1754943508222875e-38f

static __device__ __forceinline__ float f_add(float a, float b){ return __fadd_rn(a,b); }
static __device__ __forceinline__ float f_mul(float a, float b){ return __fmul_rn(a,b); }
static __device__ __forceinline__ float f_sub(float a, float b){ return __fsub_rn(a,b); }

static __device__ __forceinline__ double shfl_xor_d(double v, int mask) {
  long long x = __double_as_longlong(v);
  int lo = (int)(x & 0xffffffffll);
  int hi = (int)(x >> 32);
  lo = __shfl_xor(lo, mask);
  hi = __shfl_xor(hi, mask);
  return __longlong_as_double(((long long)hi << 32) | (unsigned long long)(unsigned int)lo);
}
#define RED2(x) { x += shfl_xor_d(x, 16); x += shfl_xor_d(x, 32); }

// XLA CPU tanh: elemental_ir_emitter rational approximation, unfused mul/add.
static __device__ __forceinline__ float tanh_xla(float x) {
  float xc = fminf(fmaxf(x, -7.90531110763549805f), 7.90531110763549805f);
  float x2 = f_mul(xc, xc);
  float p;
  p = -2.76076847742355e-16f;
  p = f_add(f_mul(p, x2),  2.00018790482477e-13f);
  p = f_add(f_mul(p, x2), -8.60467152213735e-11f);
  p = f_add(f_mul(p, x2),  5.12229709037114e-08f);
  p = f_add(f_mul(p, x2),  1.48572235717979e-05f);
  p = f_add(f_mul(p, x2),  6.37261928875436e-04f);
  p = f_add(f_mul(p, x2),  4.89352455891786e-03f);
  p = f_mul(xc, p);
  float q;
  q = 1.19825839466702e-06f;
  q = f_add(f_mul(q, x2), 1.18534705686654e-04f);
  q = f_add(f_mul(q, x2), 2.26843463243900e-03f);
  q = f_add(f_mul(q, x2), 4.89352518554385e-03f);
  float r = __fdiv_rn(p, q);
  return (fabsf(x) < 0.0004f) ? x : r;
}

// XLA logistic expansion: 0.5 + 0.5*tanh(0.5*x)
static __device__ __forceinline__ float sigmoid_xla(float x) {
  return f_add(0.5f, f_mul(0.5f, tanh_xla(f_mul(0.5f, x))));
}

// Threefry-2x32, 20 rounds (JAX key schedule)
static __device__ __forceinline__ void tf2x32(uint32_t k0, uint32_t k1,
                                              uint32_t x0, uint32_t x1,
                                              uint32_t &o0, uint32_t &o1) {
  uint32_t ks2 = k0 ^ k1 ^ 0x1BD11BDAu;
  x0 += k0; x1 += k1;
#define TFR(r) { x0 += x1; x1 = (x1 << (r)) | (x1 >> (32 - (r))); x1 ^= x0; }
  TFR(13) TFR(15) TFR(26) TFR(6)
  x0 += k1;  x1 += ks2 + 1u;
  TFR(17) TFR(29) TFR(16) TFR(24)
  x0 += ks2; x1 += k0 + 2u;
  TFR(13) TFR(15) TFR(26) TFR(6)
  x0 += k0;  x1 += k1 + 3u;
  TFR(17) TFR(29) TFR(16) TFR(24)
  x0 += k1;  x1 += ks2 + 4u;
  TFR(13) TFR(15) TFR(26) TFR(6)
  x0 += ks2; x1 += k0 + 5u;
#undef TFR
  o0 = x0; o1 = x1;
}

// NOTE: parameter names must not collide with float4 member names (.x/.y/.z/.w)
#define ACC4(acc, Wv, Vv) \
  acc = fma((double)(Wv).x, (double)(Vv).x, acc); \
  acc = fma((double)(Wv).y, (double)(Vv).y, acc); \
  acc = fma((double)(Wv).z, (double)(Vv).z, acc); \
  acc = fma((double)(Wv).w, (double)(Vv).w, acc);

// Pack weights: LSTM [512,128] -> P[(k>>2)*2048 + r*4 + (k&3)]
//               attn [128,128] -> P[(k>>2)*512  + o*4 + (k&3)]
__global__ void prep_kernel(const float* __restrict__ eWih, const float* __restrict__ eWhh,
                            const float* __restrict__ dWih, const float* __restrict__ dWhh,
                            const float* __restrict__ gWq,  const float* __restrict__ gWref,
                            const float* __restrict__ pWq,  const float* __restrict__ pWref,
                            float* __restrict__ ws) {
  int id = blockIdx.x * blockDim.x + threadIdx.x;
  if (id < 262144) {
    int m = id >> 16, e = id & 65535;
    const float* src = (m == 0) ? eWih : (m == 1) ? eWhh : (m == 2) ? dWih : dWhh;
    int r = e >> 7, k = e & 127;
    ws[m * 65536 + (k >> 2) * 2048 + r * 4 + (k & 3)] = src[e];
  } else if (id < 327680) {
    int a = id - 262144;
    int m = a >> 14, e = a & 16383;
    const float* src = (m == 0) ? gWq : (m == 1) ? gWref : (m == 2) ? pWq : pWref;
    int o = e >> 7, k = e & 127;
    ws[262144 + m * 16384 + (k >> 2) * 512 + o * 4 + (k & 3)] = src[e];
  }
}

// Stride-4 quarter-k LSTM step, single batch element. k4 = 4*kk + q.
// All lanes end with full sums (butterfly) -> gate math replicated x4.
static __device__ __forceinline__ float lstm_q(
    int u, int q,
    const float4* __restrict__ PIH, const float4* __restrict__ PHH,
    const float* __restrict__ bih, const float* __restrict__ bhh,
    const float4* __restrict__ xr, const float4* __restrict__ hr,
    float &c)
{
  double di = 0, df = 0, dg = 0, dd = 0;
  double ei = 0, ef = 0, eg = 0, eo = 0;
#pragma unroll 2
  for (int kk = 0; kk < 8; kk++) {
    const int k4 = 4 * kk + q;            // linear stride-4: strength-reducible
    float4 xv = xr[k4];
    float4 hv = hr[k4];
    float4 w0 = PIH[k4 * 512 + u];
    float4 w1 = PIH[k4 * 512 + u + 128];
    float4 w2 = PIH[k4 * 512 + u + 256];
    float4 w3 = PIH[k4 * 512 + u + 384];
    ACC4(di, w0, xv) ACC4(df, w1, xv) ACC4(dg, w2, xv) ACC4(dd, w3, xv)
    float4 v0 = PHH[k4 * 512 + u];
    float4 v1 = PHH[k4 * 512 + u + 128];
    float4 v2 = PHH[k4 * 512 + u + 256];
    float4 v3 = PHH[k4 * 512 + u + 384];
    ACC4(ei, v0, hv) ACC4(ef, v1, hv) ACC4(eg, v2, hv) ACC4(eo, v3, hv)
  }
  RED2(di) RED2(df) RED2(dg) RED2(dd)
  RED2(ei) RED2(ef) RED2(eg) RED2(eo)
  // ((x@Wih^T + bih) + h@Whh^T) + bhh  -- XLA add tree order
  float gi = f_add(f_add(f_add((float)di, bih[u      ]), (float)ei), bhh[u      ]);
  float gf = f_add(f_add(f_add((float)df, bih[u + 128]), (float)ef), bhh[u + 128]);
  float gg = f_add(f_add(f_add((float)dg, bih[u + 256]), (float)eg), bhh[u + 256]);
  float go = f_add(f_add(f_add((float)dd, bih[u + 384]), (float)eo), bhh[u + 384]);
  float I = sigmoid_xla(gi);
  float F = sigmoid_xla(gf);
  float G = tanh_xla(gg);
  float O = sigmoid_xla(go);
  c = f_add(f_mul(F, c), f_mul(I, G));
  return f_mul(O, tanh_xla(c));
}

__global__ void __launch_bounds__(512)
pnet_kernel(const float* __restrict__ bi, const float* __restrict__ emb,
            const float* __restrict__ ebih, const float* __restrict__ ebhh,
            const float* __restrict__ dbih, const float* __restrict__ dbhh,
            const float* __restrict__ gbq, const float* __restrict__ gbref, const float* __restrict__ gV,
            const float* __restrict__ pbq, const float* __restrict__ pbref, const float* __restrict__ pV,
            const float* __restrict__ dstart,
            float* __restrict__ ws, float* __restrict__ out)
{
  __shared__ __align__(16) float sRG[50 * RSTR];   // 26.4 KB
  __shared__ __align__(16) float sRP[50 * RSTR];   // 26.4 KB
  __shared__ __align__(16) float sh_x[128];
  __shared__ __align__(16) float sh_h[128];
  __shared__ __align__(16) float sh_q[128];
  __shared__ __align__(16) float sh_q2[128];
  __shared__ float sh_att[64];
  __shared__ float sh_w[64];
  __shared__ unsigned long long sh_msk;
  __shared__ int sh_idx;

  const int tid = threadIdx.x;              // 0..511
  const int l   = tid & 63;                 // lane
  const int w   = tid >> 6;                 // wave 0..7
  const int u   = w * 16 + (l & 15);        // unit 0..127
  const int q   = l >> 4;                   // k-quarter 0..3 (stride-4 k4)
  const bool wr = (q == 0);                 // writer lanes
  const int gb  = blockIdx.x;               // batch element

  const float4* PIH_E = (const float4*)(ws + OFF_PIH_E);
  const float4* PHH_E = (const float4*)(ws + OFF_PHH_E);
  const float4* PIH_D = (const float4*)(ws + OFF_PIH_D);
  const float4* PHH_D = (const float4*)(ws + OFF_PHH_D);
  const float4* PQG = (const float4*)(ws + OFF_PQG);
  const float4* PRG = (const float4*)(ws + OFF_PRG);
  const float4* PQP = (const float4*)(ws + OFF_PQP);
  const float4* PRP = (const float4*)(ws + OFF_PRP);

  const float NEG_INF = -__builtin_inff();

  if (tid < 128) sh_h[tid] = 0.0f;
  if (tid == 0) sh_msk = 0ull;
  float c_st = 0.0f;                        // cell state (replicated x4 lanes)
  __syncthreads();

  // ---------------- encoder + fused ref projections ----------------
  for (int t = 0; t < 50; t++) {
    if (tid < 128) {
      float x0 = bi[gb * 100 + t];
      float x1 = bi[gb * 100 + 50 + t];
      sh_x[tid] = __fmaf_rn(x1, emb[128 + tid], f_mul(x0, emb[tid]));
    }
    __syncthreads();                               // E1: x ready
    float hn = lstm_q(u, q, PIH_E, PHH_E, ebih, ebhh,
                      (const float4*)sh_x, (const float4*)sh_h, c_st);
    __syncthreads();                               // E2: dots done, h free
    if (wr) sh_h[u] = hn;
    __syncthreads();                               // E3: h ready
    // rg/rp[t][u] (Conv1d k=1 fused), stride-4 k4
    {
      double ag = 0, ap = 0;
      const float4* hr = (const float4*)sh_h;
#pragma unroll 2
      for (int kk = 0; kk < 8; kk++) {
        const int k4 = 4 * kk + q;
        float4 wg = PRG[k4 * 128 + u];
        float4 wp = PRP[k4 * 128 + u];
        float4 hv = hr[k4];
        ACC4(ag, wg, hv) ACC4(ap, wp, hv)
      }
      RED2(ag) RED2(ap)
      if (wr) {
        sRG[t * RSTR + u] = f_add((float)ag, gbref[u]);
        sRP[t * RSTR + u] = f_add((float)ap, pbref[u]);
      }
    }
    // loop-top sh_x write guarded by E1; refproj ignores sh_x.
  }
  if (tid < 128) sh_x[tid] = dstart[tid];   // decoder initial input
  __syncthreads();

  // ---------------- decoder ----------------
  for (int t = 0; t < 50; t++) {
    // partitionable threefry:
    //   fk = fold_in(key(42), t) = tf((0,42), (0,t))
    //   k1 = split(fk, 2)[0]     = tf(fk, (0,0))   [foldlike: both words]
    uint32_t f0, f1, k1a, k1b;
    tf2x32(0u, 42u, 0u, (uint32_t)t, f0, f1);
    tf2x32(f0, f1, 0u, 0u, k1a, k1b);

    float hn = lstm_q(u, q, PIH_D, PHH_D, dbih, dbhh,
                      (const float4*)sh_x, (const float4*)sh_h, c_st);
    __syncthreads();                               // B1: dots done
    if (wr) sh_h[u] = hn;
    __syncthreads();                               // B2: h ready

    // glimpse query: qg = Wq_g @ h + bq_g (stride-4 k4)
    {
      double a = 0;
      const float4* hr = (const float4*)sh_h;
#pragma unroll 2
      for (int kk = 0; kk < 8; kk++) {
        const int k4 = 4 * kk + q;
        float4 wv = PQG[k4 * 128 + u];
        float4 xv = hr[k4];
        ACC4(a, wv, xv)
      }
      RED2(a)
      if (wr) sh_q[u] = f_add((float)a, gbq[u]);
    }
    __syncthreads();                               // B3

    // glimpse logits: lg[s] = sum_h V[h]*tanh(qg[h]+ref_g[s][h]); 8 lanes/row
    {
      double acc = 0.0;
      const int s = tid >> 3;
      const int f4o = (tid & 7) * 4;
      if (tid < 400) {
        const float4* rr = (const float4*)(&sRG[s * RSTR]) + f4o;
        const float4* qq = (const float4*)sh_q + f4o;
        const float4* vvp = (const float4*)gV + f4o;
#pragma unroll
        for (int k4 = 0; k4 < 4; k4++) {
          float4 rv = rr[k4];
          float4 qv = qq[k4];
          float4 gvv = vvp[k4];
          acc = fma((double)gvv.x, (double)tanh_xla(f_add(qv.x, rv.x)), acc);
          acc = fma((double)gvv.y, (double)tanh_xla(f_add(qv.y, rv.y)), acc);
          acc = fma((double)gvv.z, (double)tanh_xla(f_add(qv.z, rv.z)), acc);
          acc = fma((double)gvv.w, (double)tanh_xla(f_add(qv.w, rv.w)), acc);
        }
      }
      double tot = acc + shfl_xor_d(acc, 1);
      tot = tot + shfl_xor_d(tot, 2);
      tot = tot + shfl_xor_d(tot, 4);
      if (tid < 400 && (tid & 7) == 0) {
        float lg = (float)tot;
        sh_att[s] = ((sh_msk >> s) & 1ull) ? NEG_INF : lg;
      }
      if (tid >= 400 && tid < 414) sh_att[tid - 350] = NEG_INF;  // pad 50..63
    }
    __syncthreads();                               // B4

    // glimpse softmax: wave 0
    if (w == 0) {
      float v = sh_att[l];
      float m = v;
      for (int off = 32; off > 0; off >>= 1) m = fmaxf(m, __shfl_xor(m, off));
      float ex = (l < 50) ? expf(f_sub(v, m)) : 0.0f;
      float ss = 0.0f;
      for (int s2 = 0; s2 < 50; s2++) ss = f_add(ss, __shfl(ex, s2));
      float wv = __fdiv_rn(ex, ss);
      sh_w[l] = (l < 50) ? wv : 0.0f;
    }
    __syncthreads();                               // B5

    // q2 = sum_s w[s]*ref_g[s][:]; s-halves by (q&1), combine xor16
    {
      double a = 0;
      const int s0 = (q & 1) * 25;
      for (int s2 = s0; s2 < s0 + 25; s2++) {
        a = fma((double)sRG[s2 * RSTR + u], (double)sh_w[s2], a);
      }
      a += shfl_xor_d(a, 16);
      if (wr) sh_q2[u] = (float)a;
    }
    __syncthreads();                               // B6

    // pointer query: qp = Wq_p @ q2 + bq_p (stride-4 k4)
    {
      double a = 0;
      const float4* qr = (const float4*)sh_q2;
#pragma unroll 2
      for (int kk = 0; kk < 8; kk++) {
        const int k4 = 4 * kk + q;
        float4 wv = PQP[k4 * 128 + u];
        float4 xv = qr[k4];
        ACC4(a, wv, xv)
      }
      RED2(a)
      if (wr) sh_q[u] = f_add((float)a, pbq[u]);
    }
    __syncthreads();                               // B7

    // pointer logits + 10*tanh + mask; 8 lanes/row
    {
      double acc = 0.0;
      const int s = tid >> 3;
      const int f4o = (tid & 7) * 4;
      if (tid < 400) {
        const float4* rr = (const float4*)(&sRP[s * RSTR]) + f4o;
        const float4* qq = (const float4*)sh_q + f4o;
        const float4* vvp = (const float4*)pV + f4o;
#pragma unroll
        for (int k4 = 0; k4 < 4; k4++) {
          float4 rv = rr[k4];
          float4 qv = qq[k4];
          float4 pvv = vvp[k4];
          acc = fma((double)pvv.x, (double)tanh_xla(f_add(qv.x, rv.x)), acc);
          acc = fma((double)pvv.y, (double)tanh_xla(f_add(qv.y, rv.y)), acc);
          acc = fma((double)pvv.z, (double)tanh_xla(f_add(qv.z, rv.z)), acc);
          acc = fma((double)pvv.w, (double)tanh_xla(f_add(qv.w, rv.w)), acc);
        }
      }
      double tot = acc + shfl_xor_d(acc, 1);
      tot = tot + shfl_xor_d(tot, 2);
      tot = tot + shfl_xor_d(tot, 4);
      if (tid < 400 && (tid & 7) == 0) {
        float lp = (float)tot;
        lp = f_mul(10.0f, tanh_xla(lp));
        sh_att[s] = ((sh_msk >> s) & 1ull) ? NEG_INF : lp;
      }
      if (tid >= 400 && tid < 414) sh_att[tid - 350] = NEG_INF;
    }
    __syncthreads();                               // B8

    // probs output + gumbel sampling: wave 0
    if (w == 0) {
      float v = sh_att[l];
      float m = v;
      for (int off = 32; off > 0; off >>= 1) m = fmaxf(m, __shfl_xor(m, off));
      float ex = (l < 50) ? expf(f_sub(v, m)) : 0.0f;
      float ss = 0.0f;
      for (int s2 = 0; s2 < 50; s2++) ss = f_add(ss, __shfl(ex, s2));
      if (l < 50) out[t * 25600 + gb * 50 + l] = __fdiv_rn(ex, ss);

      float val = NEG_INF;
      int ii = l;
      if (l < 50) {
        int j = gb * 50 + l;               // flat index into (B,S) gumbel draw
        uint32_t b0, b1;
        tf2x32(k1a, k1b, 0u, (uint32_t)j, b0, b1);
        uint32_t bits = b0 ^ b1;
        float fl = __uint_as_float((bits >> 9) | 0x3f800000u) - 1.0f;  // [0,1)
        float uu = f_add(fl, TINYF);
        uu = fmaxf(TINYF, uu);
        float gum = -logf(-logf(uu));
        val = f_add(v, gum);               // -inf stays -inf for masked
      }
      // argmax, first-index tiebreak (jnp.argmax semantics)
      for (int off = 32; off > 0; off >>= 1) {
        float ov = __shfl_down(val, off);
        int   oi = __shfl_down(ii, off);
        if (ov > val || (ov == val && oi < ii)) { val = ov; ii = oi; }
      }
      if (l == 0) {
        sh_idx = ii;
        sh_msk |= (1ull << ii);            // masks step t+1 onward
        out[1280000 + t * 512 + gb] = (float)ii;
      }
    }
    __syncthreads();                               // B9

    // next decoder input: embedded[b, idx]
    if (tid < 128) {
      int idx = sh_idx;
      float x0 = bi[gb * 100 + idx];
      float x1 = bi[gb * 100 + 50 + idx];
      sh_x[tid] = __fmaf_rn(x1, emb[128 + tid], f_mul(x0, emb[tid]));
    }
    __syncthreads();                               // B10
  }
}

extern "C" void kernel_launch(void* const* d_in, const int* in_sizes, int n_in,
                              void* d_out, int out_size, void* d_ws, size_t ws_size,
                              hipStream_t stream) {
  const float* bi     = (const float*)d_in[0];
  const float* emb    = (const float*)d_in[1];
  const float* eWih   = (const float*)d_in[2];
  const float* eWhh   = (const float*)d_in[3];
  const float* ebih   = (const float*)d_in[4];
  const float* ebhh   = (const float*)d_in[5];
  const float* dWih   = (const float*)d_in[6];
  const float* dWhh   = (const float*)d_in[7];
  const float* dbih   = (const float*)d_in[8];
  const float* dbhh   = (const float*)d_in[9];
  const float* gWq    = (const float*)d_in[10];
  const float* gbq    = (const float*)d_in[11];
  const float* gWref  = (const float*)d_in[12];
  const float* gbref  = (const float*)d_in[13];
  const float* gV     = (const float*)d_in[14];
  const float* pWq    = (const float*)d_in[15];
  const float* pbq    = (const float*)d_in[16];
  const float* pWref  = (const float*)d_in[17];
  const float* pbref  = (const float*)d_in[18];
  const float* pV     = (const float*)d_in[19];
  const float* dstart = (const float*)d_in[20];
  float* ws  = (float*)d_ws;
  float* out = (float*)d_out;

  hipLaunchKernelGGL(prep_kernel, dim3(1280), dim3(256), 0, stream,
                     eWih, eWhh, dWih, dWhh, gWq, gWref, pWq, pWref, ws);
  hipLaunchKernelGGL(pnet_kernel, dim3(512), dim3(512), 0, stream,
                     bi, emb, ebih, ebhh, dbih, dbhh,
                     gbq, gbref, gV, pbq, pbref, pV, dstart, ws, out);
}